// Round 8
// baseline (161.485 us; speedup 1.0000x reference)
//
#include <hip/hip_runtime.h>
#include <math.h>

#define EPS   1e-6f
#define K_V   0.4052847345693511f   /* 4/pi^2 */
#define IMG2  369664.0f             /* 608^2 */
#define NBOX  150
#define NBOXP 152                   /* padded: 8 octants x 19 boxes */
#define NCLS  20

// 32 anchors per block, 8 lanes per anchor (octant o scans boxes o*19..o*19+18)
#define APB0  17328
#define APB1  4332
#define APB2  1083
#define BPB_L0 542   /* ceil(17328/32) */
#define BPB_L1 136   /* ceil(4332/32)  */
#define BPB_L2 34    /* ceil(1083/32)  */
#define NBLK  (4*(BPB_L0+BPB_L1+BPB_L2))   /* 2848 */

__device__ __forceinline__ float fast_rcp(float x) { return __builtin_amdgcn_rcpf(x); }

__device__ __forceinline__ float bce_logits(float x, float t) {
    // logaddexp(0,x) - x*t via hw exp/log; |err| ~1e-7*|val|, threshold is 591.
    float e = __expf(-fabsf(x));
    return fmaxf(x, 0.f) + __logf(1.f + e) - x * t;
}

__device__ __forceinline__ float wave_sum(float v) {
#pragma unroll
    for (int off = 32; off > 0; off >>= 1) v += __shfl_down(v, off, 64);
    return v;
}

__global__ __launch_bounds__(256, 8) void yolo_loss_kernel(
    const float* __restrict__ p0,  const float* __restrict__ pd0,
    const float* __restrict__ lb0, const float* __restrict__ bb0,
    const float* __restrict__ p1,  const float* __restrict__ pd1,
    const float* __restrict__ lb1, const float* __restrict__ bb1,
    const float* __restrict__ p2,  const float* __restrict__ pd2,
    const float* __restrict__ lb2, const float* __restrict__ bb2,
    float* __restrict__ ws, float* __restrict__ out)
{
    __shared__ float4 s_box[NBOXP];   // lox, loy, hix, hiy
    __shared__ float4 s_aux[NBOXP];   // area, cx, cy, atan(w/h)
    __shared__ float  s_part[4][3];

    const int blk = blockIdx.x;
    const float *p, *pd, *lb, *bb;
    int batch, lblk, apb;
    if (blk < 4*BPB_L0) {
        p = p0; pd = pd0; lb = lb0; bb = bb0;
        batch = blk / BPB_L0; lblk = blk % BPB_L0; apb = APB0;
    } else if (blk < 4*(BPB_L0+BPB_L1)) {
        int r = blk - 4*BPB_L0;
        p = p1; pd = pd1; lb = lb1; bb = bb1;
        batch = r / BPB_L1; lblk = r % BPB_L1; apb = APB1;
    } else {
        int r = blk - 4*(BPB_L0+BPB_L1);
        p = p2; pd = pd2; lb = lb2; bb = bb2;
        batch = r / BPB_L2; lblk = r % BPB_L2; apb = APB2;
    }

    const int tid  = threadIdx.x;
    const int wave = tid >> 6, lane = tid & 63;
    const int o = lane >> 3, s = lane & 7;        // octant, anchor-slot
    const int arow = lblk * 32 + wave * 8 + s;    // anchor row in this batch
    const bool active = (arow < apb);
    const int rowc = min(arow, apb - 1);          // clamped: loads always valid
    const size_t base = (size_t)batch * apb + rowc;

    // ---- issue all gathers up front, unpredicated (clamped rows are valid
    // data; every contribution is gated by `active` later).
    float4 bxy = make_float4(3.0e30f, 3.0e30f, 0.f, 1.f);
    if (tid < NBOX) bxy = ((const float4*)bb)[batch * NBOX + tid];  // 16B aligned

    const float* pdp = pd + base * 25;
    const float* lbp = lb + base * 26;
    const float b1x = pdp[0], b1y = pdp[1], b1w = pdp[2], b1h = pdp[3];
    const float2 om = *(const float2*)(lbp + 4);   // 104B row stride, 8B aligned
    const float obj = om.x, mix = om.y;
    const float pconf = p[base * 25 + 4];

    // ---- stage gt boxes (150 + 2 degenerate pads) ----
    if (tid < NBOXP) {
        float hw = bxy.z * 0.5f, hh = bxy.w * 0.5f;
        float ltx = bxy.x - hw, lty = bxy.y - hh;
        float rbx = bxy.x + hw, rby = bxy.y + hh;
        float lox = fminf(ltx, rbx), hix = fmaxf(ltx, rbx);
        float loy = fminf(lty, rby), hiy = fmaxf(lty, rby);
        s_box[tid] = make_float4(lox, loy, hix, hiy);
        s_aux[tid] = make_float4((hix - lox) * (hiy - loy), bxy.x, bxy.y,
                                 atanf(bxy.z / fmaxf(bxy.w, EPS)));
    }
    __syncthreads();

    const float hw = b1w * 0.5f, hh = b1h * 0.5f;
    const float l1x = b1x - hw, l1y = b1y - hh;
    const float r1x = b1x + hw, r1y = b1y + hh;
    const float lo1x = fminf(l1x, r1x), hi1x = fmaxf(l1x, r1x);
    const float lo1y = fminf(l1y, r1y), hi1y = fmaxf(l1y, r1y);
    const float area1 = (hi1x - lo1x) * (hi1y - lo1y);

    // ---- phase 1: division-free pre-test over this octant's 19 boxes.
    // 2*inter >= (1-4e-6)*max(union,EPS) is necessary for fl(iou)>=0.5
    // (ciou <= iou always). Flagged boxes recorded in a 19-bit mask.
    const int j0 = o * 19;
    unsigned mask = 0u;
    if (obj == 0.f) {
#pragma unroll
        for (int k = 0; k < 19; ++k) {
            float4 b4 = s_box[j0 + k];
            float a2  = (b4.z - b4.x) * (b4.w - b4.y);
            float ix0 = fmaxf(lo1x, b4.x), iy0 = fmaxf(lo1y, b4.y);
            float ix1 = fminf(hi1x, b4.z), iy1 = fminf(hi1y, b4.w);
            float iwx = fmaxf(ix1 - ix0, 0.f);
            float iwy = fmaxf(iy1 - iy0, 0.f);
            float inter = iwx * iwy;
            float uni_m = fmaxf(area1 + a2 - inter, EPS);
            float metric = fmaf(-0.999996f, uni_m, inter + inter);
            mask |= (unsigned)(metric > 0.f) << k;
        }
    }

    // ---- phase 2: exact ciou >= 0.5 only for flagged pairs (rare)
    int hit = 0;
    if (mask) {
        const float at1 = atanf(b1w / fmaxf(b1h, EPS));
        unsigned m = mask;
        do {
            int k = __ffs(m) - 1; m &= m - 1;
            float4 b4 = s_box[j0 + k];
            float4 ax = s_aux[j0 + k];
            float ix0 = fmaxf(lo1x, b4.x), iy0 = fmaxf(lo1y, b4.y);
            float ix1 = fminf(hi1x, b4.z), iy1 = fminf(hi1y, b4.w);
            float iwx = fmaxf(ix1 - ix0, 0.f);
            float iwy = fmaxf(iy1 - iy0, 0.f);
            float inter = iwx * iwy;
            float iou = inter * fast_rcp(fmaxf(area1 + ax.x - inter, EPS));
            float owx = fmaxf(hi1x, b4.z) - fminf(lo1x, b4.x);
            float owy = fmaxf(hi1y, b4.w) - fminf(lo1y, b4.y);
            float c2 = fmaxf(owx * owx + owy * owy, EPS);
            float dx = b1x - ax.y, dy = b1y - ax.z;
            float u = (dx * dx + dy * dy) * fast_rcp(c2);
            float dv = ax.w - at1;
            float v = K_V * dv * dv;
            float alpha = v * fast_rcp(fmaxf(1.f - iou + v, EPS));
            float ci = iou - (u + alpha * v);
            hit |= (ci >= 0.5f);
        } while (m);
    }
    hit |= __shfl_xor(hit, 8, 64);    // combine the 8 box octants
    hit |= __shfl_xor(hit, 16, 64);
    hit |= __shfl_xor(hit, 32, 64);

    // ---- per-anchor outputs ----
    float t_ciou = 0.f, t_conf = 0.f, t_cls = 0.f;
    if (active && obj > 0.f) {
        // class BCE strided across the anchor's 8 octant-lanes; the wave
        // reduction sums the partials exactly once.
        float cs = 0.f;
        const float* pc = p + base * 25 + 5;
        const float* lc = lbp + 6;
        for (int c = o; c < NCLS; c += 8) cs += bce_logits(pc[c], lc[c]);
        t_cls = cs * mix;
    }
    if (active && o == 0) {
        const float sig = fast_rcp(1.f + __expf(-pconf));
        const float dd = fabsf(obj - sig);
        const float focal = bce_logits(pconf, obj) * (dd * dd); // ALPHA=1,GAMMA=2
        float gate;
        if (obj > 0.f) {
            const float at1 = atanf(b1w / fmaxf(b1h, EPS));
            const float2 lxy = *(const float2*)(lbp + 0);   // 8B aligned
            const float2 lwh = *(const float2*)(lbp + 2);
            const float lx = lxy.x, ly = lxy.y, lw = lwh.x, lh = lwh.y;
            const float hlw = lw * 0.5f, hlh = lh * 0.5f;
            const float l2x = lx - hlw, l2y = ly - hlh;
            const float r2x = lx + hlw, r2y = ly + hlh;
            const float lo2x = fminf(l2x, r2x), hi2x = fmaxf(l2x, r2x);
            const float lo2y = fminf(l2y, r2y), hi2y = fmaxf(l2y, r2y);
            const float area2 = (hi2x - lo2x) * (hi2y - lo2y);
            float iwx = fmaxf(fminf(hi1x, hi2x) - fmaxf(lo1x, lo2x), 0.f);
            float iwy = fmaxf(fminf(hi1y, hi2y) - fmaxf(lo1y, lo2y), 0.f);
            float inter = iwx * iwy;
            float iou = inter * fast_rcp(fmaxf(area1 + area2 - inter, EPS));
            float owx = fmaxf(hi1x, hi2x) - fminf(lo1x, lo2x);
            float owy = fmaxf(hi1y, hi2y) - fminf(lo1y, lo2y);
            float c2 = fmaxf(owx * owx + owy * owy, EPS);
            float dx = b1x - lx, dy = b1y - ly;
            float u = (dx * dx + dy * dy) * fast_rcp(c2);
            float at2 = atanf(lw / fmaxf(lh, EPS));
            float dv = at2 - at1;
            float v = K_V * dv * dv;
            float alpha = v * fast_rcp(fmaxf(1.f - iou + v, EPS));
            float ciou = iou - (u + alpha * v);
            float scale = 2.f - lw * lh * (1.f / IMG2);
            t_ciou = scale * (1.f - ciou) * mix;
            gate = 1.f;
        } else {
            gate = hit ? 0.f : 1.f;
        }
        t_conf = gate * focal * mix;
    }

    // ---- block reduction: wave shuffle -> LDS -> 3 atomics per block ----
    float r0 = wave_sum(t_ciou);
    float r1 = wave_sum(t_conf);
    float r2 = wave_sum(t_cls);
    if (lane == 0) { s_part[wave][0] = r0; s_part[wave][1] = r1; s_part[wave][2] = r2; }
    __syncthreads();

    if (tid == 0) {
        float c = 0.f, f = 0.f, cl = 0.f;
#pragma unroll
        for (int w = 0; w < 4; ++w) { c += s_part[w][0]; f += s_part[w][1]; cl += s_part[w][2]; }
        const int slot = (blk & 7) * 16;      // 8 XCD-strided slots, 64B apart
        atomicAdd(&ws[slot + 0], c);
        atomicAdd(&ws[slot + 1], f);
        atomicAdd(&ws[slot + 2], cl);
        __threadfence();
        unsigned old = atomicAdd((unsigned*)(ws + 128), 1u);
        if (old == NBLK - 1) {
            __threadfence();
            float C = 0.f, F = 0.f, CL = 0.f;
#pragma unroll
            for (int sl = 0; sl < 8; ++sl) {
                C  += atomicAdd(&ws[sl*16 + 0], 0.f);   // coherent L2 reads
                F  += atomicAdd(&ws[sl*16 + 1], 0.f);
                CL += atomicAdd(&ws[sl*16 + 2], 0.f);
            }
            const float inv_bs = 0.25f;   // bs = 4 for every layer
            out[0] = (C + F + CL) * inv_bs;
            out[1] = C * inv_bs;
            out[2] = F * inv_bs;
            out[3] = CL * inv_bs;
        }
    }
}

extern "C" void kernel_launch(void* const* d_in, const int* in_sizes, int n_in,
                              void* d_out, int out_size, void* d_ws, size_t ws_size,
                              hipStream_t stream) {
    const float* p0  = (const float*)d_in[0];
    const float* pd0 = (const float*)d_in[1];
    const float* lb0 = (const float*)d_in[2];
    const float* bb0 = (const float*)d_in[3];
    const float* p1  = (const float*)d_in[4];
    const float* pd1 = (const float*)d_in[5];
    const float* lb1 = (const float*)d_in[6];
    const float* bb1 = (const float*)d_in[7];
    const float* p2  = (const float*)d_in[8];
    const float* pd2 = (const float*)d_in[9];
    const float* lb2 = (const float*)d_in[10];
    const float* bb2 = (const float*)d_in[11];

    float* ws = (float*)d_ws;
    hipMemsetAsync(ws, 0, 132 * sizeof(float), stream);  // 8 slots + done counter

    yolo_loss_kernel<<<NBLK, 256, 0, stream>>>(
        p0, pd0, lb0, bb0, p1, pd1, lb1, bb1, p2, pd2, lb2, bb2,
        ws, (float*)d_out);
}

// Round 9
// 105.269 us; speedup vs baseline: 1.5340x; 1.5340x over previous
//
#include <hip/hip_runtime.h>
#include <math.h>

#define EPS   1e-6f
#define K_V   0.4052847345693511f   /* 4/pi^2 */
#define IMG2  369664.0f             /* 608^2 */
#define NBOX  150
#define NBOXP 152                   /* padded: 8 octants x 19 boxes */
#define NCLS  20

// 32 anchors per block, 8 lanes per anchor (octant o scans boxes o*19..o*19+18)
#define APB0  17328
#define APB1  4332
#define APB2  1083
#define BPB_L0 542   /* ceil(17328/32) */
#define BPB_L1 136   /* ceil(4332/32)  */
#define BPB_L2 34    /* ceil(1083/32)  */
#define NBLK  (4*(BPB_L0+BPB_L1+BPB_L2))   /* 2848 */

__device__ __forceinline__ float fast_rcp(float x) { return __builtin_amdgcn_rcpf(x); }

__device__ __forceinline__ float bce_logits(float x, float t) {
    // logaddexp(0,x) - x*t via hw exp/log; |err| ~1e-7*|val|, threshold is 591.
    float e = __expf(-fabsf(x));
    return fmaxf(x, 0.f) + __logf(1.f + e) - x * t;
}

__device__ __forceinline__ float wave_sum(float v) {
#pragma unroll
    for (int off = 32; off > 0; off >>= 1) v += __shfl_down(v, off, 64);
    return v;
}

__global__ __launch_bounds__(256, 8) void yolo_loss_kernel(
    const float* __restrict__ p0,  const float* __restrict__ pd0,
    const float* __restrict__ lb0, const float* __restrict__ bb0,
    const float* __restrict__ p1,  const float* __restrict__ pd1,
    const float* __restrict__ lb1, const float* __restrict__ bb1,
    const float* __restrict__ p2,  const float* __restrict__ pd2,
    const float* __restrict__ lb2, const float* __restrict__ bb2,
    float4* __restrict__ ws4)
{
    __shared__ float4 s_box[NBOXP];   // lox, loy, hix, hiy
    __shared__ float4 s_aux[NBOXP];   // area, cx, cy, atan(w/h)
    __shared__ float  s_part[4][3];

    const int blk = blockIdx.x;
    const float *p, *pd, *lb, *bb;
    int batch, lblk, apb;
    if (blk < 4*BPB_L0) {
        p = p0; pd = pd0; lb = lb0; bb = bb0;
        batch = blk / BPB_L0; lblk = blk % BPB_L0; apb = APB0;
    } else if (blk < 4*(BPB_L0+BPB_L1)) {
        int r = blk - 4*BPB_L0;
        p = p1; pd = pd1; lb = lb1; bb = bb1;
        batch = r / BPB_L1; lblk = r % BPB_L1; apb = APB1;
    } else {
        int r = blk - 4*(BPB_L0+BPB_L1);
        p = p2; pd = pd2; lb = lb2; bb = bb2;
        batch = r / BPB_L2; lblk = r % BPB_L2; apb = APB2;
    }

    const int tid  = threadIdx.x;
    const int wave = tid >> 6, lane = tid & 63;
    const int o = lane >> 3, s = lane & 7;        // octant, anchor-slot
    const int arow = lblk * 32 + wave * 8 + s;    // anchor row in this batch
    const bool active = (arow < apb);
    const int rowc = min(arow, apb - 1);          // clamped: loads always valid
    const size_t base = (size_t)batch * apb + rowc;

    // ---- issue all gathers up front, unpredicated (clamped rows are valid
    // data; every contribution is gated by `active` later).
    float4 bxy = make_float4(3.0e30f, 3.0e30f, 0.f, 1.f);
    if (tid < NBOX) bxy = ((const float4*)bb)[batch * NBOX + tid];  // 16B aligned

    const float* pdp = pd + base * 25;
    const float* lbp = lb + base * 26;
    const float b1x = pdp[0], b1y = pdp[1], b1w = pdp[2], b1h = pdp[3];
    const float2 om = *(const float2*)(lbp + 4);   // 104B row stride, 8B aligned
    const float obj = om.x, mix = om.y;
    const float pconf = p[base * 25 + 4];

    // ---- stage gt boxes (150 + 2 degenerate pads) ----
    if (tid < NBOXP) {
        float hw = bxy.z * 0.5f, hh = bxy.w * 0.5f;
        float ltx = bxy.x - hw, lty = bxy.y - hh;
        float rbx = bxy.x + hw, rby = bxy.y + hh;
        float lox = fminf(ltx, rbx), hix = fmaxf(ltx, rbx);
        float loy = fminf(lty, rby), hiy = fmaxf(lty, rby);
        s_box[tid] = make_float4(lox, loy, hix, hiy);
        s_aux[tid] = make_float4((hix - lox) * (hiy - loy), bxy.x, bxy.y,
                                 atanf(bxy.z / fmaxf(bxy.w, EPS)));
    }
    __syncthreads();

    const float hw = b1w * 0.5f, hh = b1h * 0.5f;
    const float l1x = b1x - hw, l1y = b1y - hh;
    const float r1x = b1x + hw, r1y = b1y + hh;
    const float lo1x = fminf(l1x, r1x), hi1x = fmaxf(l1x, r1x);
    const float lo1y = fminf(l1y, r1y), hi1y = fmaxf(l1y, r1y);
    const float area1 = (hi1x - lo1x) * (hi1y - lo1y);

    // ---- phase 1: division-free pre-test over this octant's 19 boxes.
    // 2*inter >= (1-4e-6)*max(union,EPS) is necessary for fl(iou)>=0.5
    // (ciou <= iou always). Flagged boxes recorded in a 19-bit mask.
    const int j0 = o * 19;
    unsigned mask = 0u;
    if (obj == 0.f) {
#pragma unroll
        for (int k = 0; k < 19; ++k) {
            float4 b4 = s_box[j0 + k];
            float a2  = (b4.z - b4.x) * (b4.w - b4.y);
            float ix0 = fmaxf(lo1x, b4.x), iy0 = fmaxf(lo1y, b4.y);
            float ix1 = fminf(hi1x, b4.z), iy1 = fminf(hi1y, b4.w);
            float iwx = fmaxf(ix1 - ix0, 0.f);
            float iwy = fmaxf(iy1 - iy0, 0.f);
            float inter = iwx * iwy;
            float uni_m = fmaxf(area1 + a2 - inter, EPS);
            float metric = fmaf(-0.999996f, uni_m, inter + inter);
            mask |= (unsigned)(metric > 0.f) << k;
        }
    }

    // ---- phase 2: exact ciou >= 0.5 only for flagged pairs (rare)
    int hit = 0;
    if (mask) {
        const float at1 = atanf(b1w / fmaxf(b1h, EPS));
        unsigned m = mask;
        do {
            int k = __ffs(m) - 1; m &= m - 1;
            float4 b4 = s_box[j0 + k];
            float4 ax = s_aux[j0 + k];
            float ix0 = fmaxf(lo1x, b4.x), iy0 = fmaxf(lo1y, b4.y);
            float ix1 = fminf(hi1x, b4.z), iy1 = fminf(hi1y, b4.w);
            float iwx = fmaxf(ix1 - ix0, 0.f);
            float iwy = fmaxf(iy1 - iy0, 0.f);
            float inter = iwx * iwy;
            float iou = inter * fast_rcp(fmaxf(area1 + ax.x - inter, EPS));
            float owx = fmaxf(hi1x, b4.z) - fminf(lo1x, b4.x);
            float owy = fmaxf(hi1y, b4.w) - fminf(lo1y, b4.y);
            float c2 = fmaxf(owx * owx + owy * owy, EPS);
            float dx = b1x - ax.y, dy = b1y - ax.z;
            float u = (dx * dx + dy * dy) * fast_rcp(c2);
            float dv = ax.w - at1;
            float v = K_V * dv * dv;
            float alpha = v * fast_rcp(fmaxf(1.f - iou + v, EPS));
            float ci = iou - (u + alpha * v);
            hit |= (ci >= 0.5f);
        } while (m);
    }
    hit |= __shfl_xor(hit, 8, 64);    // combine the 8 box octants
    hit |= __shfl_xor(hit, 16, 64);
    hit |= __shfl_xor(hit, 32, 64);

    // ---- per-anchor outputs ----
    float t_ciou = 0.f, t_conf = 0.f, t_cls = 0.f;
    if (active && obj > 0.f) {
        // class BCE strided across the anchor's 8 octant-lanes; the wave
        // reduction sums the partials exactly once.
        float cs = 0.f;
        const float* pc = p + base * 25 + 5;
        const float* lc = lbp + 6;
        for (int c = o; c < NCLS; c += 8) cs += bce_logits(pc[c], lc[c]);
        t_cls = cs * mix;
    }
    if (active && o == 0) {
        const float sig = fast_rcp(1.f + __expf(-pconf));
        const float dd = fabsf(obj - sig);
        const float focal = bce_logits(pconf, obj) * (dd * dd); // ALPHA=1,GAMMA=2
        float gate;
        if (obj > 0.f) {
            const float at1 = atanf(b1w / fmaxf(b1h, EPS));
            const float2 lxy = *(const float2*)(lbp + 0);   // 8B aligned
            const float2 lwh = *(const float2*)(lbp + 2);
            const float lx = lxy.x, ly = lxy.y, lw = lwh.x, lh = lwh.y;
            const float hlw = lw * 0.5f, hlh = lh * 0.5f;
            const float l2x = lx - hlw, l2y = ly - hlh;
            const float r2x = lx + hlw, r2y = ly + hlh;
            const float lo2x = fminf(l2x, r2x), hi2x = fmaxf(l2x, r2x);
            const float lo2y = fminf(l2y, r2y), hi2y = fmaxf(l2y, r2y);
            const float area2 = (hi2x - lo2x) * (hi2y - lo2y);
            float iwx = fmaxf(fminf(hi1x, hi2x) - fmaxf(lo1x, lo2x), 0.f);
            float iwy = fmaxf(fminf(hi1y, hi2y) - fmaxf(lo1y, lo2y), 0.f);
            float inter = iwx * iwy;
            float iou = inter * fast_rcp(fmaxf(area1 + area2 - inter, EPS));
            float owx = fmaxf(hi1x, hi2x) - fminf(lo1x, lo2x);
            float owy = fmaxf(hi1y, hi2y) - fminf(lo1y, lo2y);
            float c2 = fmaxf(owx * owx + owy * owy, EPS);
            float dx = b1x - lx, dy = b1y - ly;
            float u = (dx * dx + dy * dy) * fast_rcp(c2);
            float at2 = atanf(lw / fmaxf(lh, EPS));
            float dv = at2 - at1;
            float v = K_V * dv * dv;
            float alpha = v * fast_rcp(fmaxf(1.f - iou + v, EPS));
            float ciou = iou - (u + alpha * v);
            float scale = 2.f - lw * lh * (1.f / IMG2);
            t_ciou = scale * (1.f - ciou) * mix;
            gate = 1.f;
        } else {
            gate = hit ? 0.f : 1.f;
        }
        t_conf = gate * focal * mix;
    }

    // ---- block reduction: wave shuffle -> LDS -> ONE plain float4 store.
    // No atomics, no return-value wait: every block owns a unique slot, so
    // the epilogue never serializes on a shared L2 line (the R4-R8 ceiling).
    float r0 = wave_sum(t_ciou);
    float r1 = wave_sum(t_conf);
    float r2 = wave_sum(t_cls);
    if (lane == 0) { s_part[wave][0] = r0; s_part[wave][1] = r1; s_part[wave][2] = r2; }
    __syncthreads();

    if (tid == 0) {
        float c = 0.f, f = 0.f, cl = 0.f;
#pragma unroll
        for (int w = 0; w < 4; ++w) { c += s_part[w][0]; f += s_part[w][1]; cl += s_part[w][2]; }
        ws4[blk] = make_float4(c, f, cl, 0.f);   // fire-and-forget store
    }
}

__global__ __launch_bounds__(256) void yolo_finalize_kernel(
    const float4* __restrict__ ws4, float* __restrict__ out)
{
    __shared__ float s_part[4][3];
    const int tid = threadIdx.x, wave = tid >> 6, lane = tid & 63;

    float c = 0.f, f = 0.f, cl = 0.f;
    for (int i = tid; i < NBLK; i += 256) {      // 12 coalesced float4 loads
        float4 v = ws4[i];
        c += v.x; f += v.y; cl += v.z;
    }
    c = wave_sum(c); f = wave_sum(f); cl = wave_sum(cl);
    if (lane == 0) { s_part[wave][0] = c; s_part[wave][1] = f; s_part[wave][2] = cl; }
    __syncthreads();

    if (tid == 0) {
        float C = 0.f, F = 0.f, CL = 0.f;
#pragma unroll
        for (int w = 0; w < 4; ++w) { C += s_part[w][0]; F += s_part[w][1]; CL += s_part[w][2]; }
        const float inv_bs = 0.25f;   // bs = 4 for every layer
        out[0] = (C + F + CL) * inv_bs;
        out[1] = C * inv_bs;
        out[2] = F * inv_bs;
        out[3] = CL * inv_bs;
    }
}

extern "C" void kernel_launch(void* const* d_in, const int* in_sizes, int n_in,
                              void* d_out, int out_size, void* d_ws, size_t ws_size,
                              hipStream_t stream) {
    const float* p0  = (const float*)d_in[0];
    const float* pd0 = (const float*)d_in[1];
    const float* lb0 = (const float*)d_in[2];
    const float* bb0 = (const float*)d_in[3];
    const float* p1  = (const float*)d_in[4];
    const float* pd1 = (const float*)d_in[5];
    const float* lb1 = (const float*)d_in[6];
    const float* bb1 = (const float*)d_in[7];
    const float* p2  = (const float*)d_in[8];
    const float* pd2 = (const float*)d_in[9];
    const float* lb2 = (const float*)d_in[10];
    const float* bb2 = (const float*)d_in[11];

    // ws4[blk] slots are written unconditionally by every block -> no memset.
    float4* ws4 = (float4*)d_ws;

    yolo_loss_kernel<<<NBLK, 256, 0, stream>>>(
        p0, pd0, lb0, bb0, p1, pd1, lb1, bb1, p2, pd2, lb2, bb2, ws4);

    yolo_finalize_kernel<<<1, 256, 0, stream>>>(ws4, (float*)d_out);
}